// Round 6
// baseline (456.044 us; speedup 1.0000x reference)
//
#include <hip/hip_runtime.h>

typedef unsigned short u16;
typedef unsigned int u32;
typedef _Float16 h16;
typedef __attribute__((ext_vector_type(2))) _Float16 half2v;
typedef __attribute__((ext_vector_type(8))) _Float16 half8;
typedef __attribute__((ext_vector_type(8))) unsigned short ushort8;
typedef __attribute__((ext_vector_type(4))) float f32x4;
typedef __attribute__((ext_vector_type(16))) float f32x16;

#define NPAIRS 15625            // 500000 / 32: each block = 4 waves = 2 strips (M=32)
#define STRIPH 12032            // h16 per strip arena (24064 B); block total 48128 B

// Planar hi/lo layout: value (row r in [0,16), col c) of buffer with stride S:
//   hi at base + r*S + c, lo at base + (16+r)*S + c. Strip 1 at +STRIPH.
#define AE1 0                   // 32 cols
#define SE1 40
#define AE2 1280                // 64 cols
#define SE2 72
#define ACT 3584                // 256 cols
#define SCT 264
#define AMR 3712                // MR (<=128 cols) ALIASED into CT cols [128:256)
#define SMR 264                 //   written only after all reads of that region

// 32x32x16 f16 MFMA: A row = lane&31, k = (lane>>5)*8+j; B col = lane&31, same k;
// C/D: col = lane&31, row = (reg&3) + 8*(reg>>2) + 4*(lane>>5)  [HW-verified map]
#define MFMA32(A,B,C) __builtin_amdgcn_mfma_f32_32x32x16_f16(A,B,C,0,0,0)

// light barrier: drain LDS ops only; global (B-prefetch) loads stay in flight
#define LBAR() asm volatile("s_waitcnt lgkmcnt(0)\n\ts_barrier" ::: "memory")
#define LWAIT() asm volatile("s_waitcnt lgkmcnt(0)" ::: "memory")

// ---------------- packed weight frag-pairs (f16 hi/lo, 32-wide tiles) ----------------
// fragpair f = FO[layer] + ct32*KS + ks, lane l, 32 B:
//   wp[(f*64+l)*16 + j]   = hi = f16(W[k][col])   (j=0..7)
//   wp[(f*64+l)*16 + 8+j] = lo = f16(W - (float)hi)
// col = ct32*32 + (l&31), k = ks*16 + (l>>5)*8 + j; zero-pad k >= K_actual.
#define F_L0   0
#define F_L1   1
#define F_L2   3
#define F_L3   7
#define F_L4   23
#define F_L5   55
#define F_L6   119
#define F_L7   135
#define F_L8   143
#define F_L9   159
#define F_L10  163
#define F_L11  165
#define F_L12  169
#define NFRAG  171              // d_ws bytes: 171*1024*2 = 350208

__device__ __forceinline__ u16 hb(h16 h) { union { h16 h; u16 u; } v; v.h = h; return v.u; }

__global__ __launch_bounds__(256) void pack_w(
    const float* w0, const float* w1, const float* w2, const float* w3, const float* w4,
    const float* w5, const float* w6, const float* w7, const float* w8, const float* w9,
    const float* w10, const float* w11, const float* w12, u16* __restrict__ packed)
{
  const float* ws[13] = {w0,w1,w2,w3,w4,w5,w6,w7,w8,w9,w10,w11,w12};
  const int Ka[13]  = {16,32,32,64,128,256,128,64,128,64,32,64,32};
  const int KS[13]  = {1,2,2,4,8,16,8,4,8,4,2,4,2};
  const int CO[13]  = {32,32,64,128,128,128,64,64,64,32,32,32,32};
  const int FO[13]  = {F_L0,F_L1,F_L2,F_L3,F_L4,F_L5,F_L6,F_L7,F_L8,F_L9,F_L10,F_L11,F_L12};
  int g = blockIdx.x * 256 + threadIdx.x;
  int f = g >> 6, lane = g & 63;
  if (f >= NFRAG) return;
  int layer = 0;
#pragma unroll
  for (int i = 1; i < 13; ++i) if (f >= FO[i]) layer = i;
  int fl = f - FO[layer];
  int ks = fl % KS[layer];
  int ct = fl / KS[layer];
  int cout = CO[layer];
  int col  = ct * 32 + (lane & 31);
  u16 thi[8], tlo[8];
#pragma unroll
  for (int j = 0; j < 8; ++j) {
    int k = ks * 16 + (lane >> 5) * 8 + j;
    float w = (k < Ka[layer]) ? ws[layer][k * cout + col] : 0.f;
    h16 h = (h16)w;
    h16 l = (h16)(w - (float)h);
    thi[j] = hb(h); tlo[j] = hb(l);
  }
  u16* dst = packed + ((size_t)f * 64 + lane) * 16;
  *(ushort8*)dst       = *(const ushort8*)thi;
  *(ushort8*)(dst + 8) = *(const ushort8*)tlo;
}

// ---------------- fused backbone ----------------

__device__ __forceinline__ void splitw(h16* dst, int idx, int dlo, float v) {
  h16 h = (h16)v;
  dst[idx]       = h;
  dst[idx + dlo] = (h16)(v - (float)h);
}

__device__ __forceinline__ float red2p(const h16* catS, int cs, int r16, int cc) {
  half2v hp = *reinterpret_cast<const half2v*>(catS + r16 * cs + 2 * cc);
  half2v lp = *reinterpret_cast<const half2v*>(catS + (r16 + 16) * cs + 2 * cc);
  return (float)hp.x + (float)hp.y + (float)lp.x + (float)lp.y;
}

// One 32x32 output tile (rows = strip pair, cols = ct*32..+31), K = KS_*16.
// A-panel read ONCE per 32 output cols; B fragpairs loaded once per block.
// EPI 0: relu->LDS | 1: +pair-red(cat) | 2: ->global fp32
// BAR=1: block barrier between all LDS reads and epilogue writes (S5 aliasing).
template<int KS_, int EPI, int BAR>
__device__ __forceinline__ void layer32(
    const h16* __restrict__ asrc, int as,
    const h16* __restrict__ wp, int foff, int ct, int lane,
    half8 pbh, half8 pbl,
    h16* dst, int ds, int colb, const h16* cat, int cs,
    float* __restrict__ gout, int row0)
{
  const int ra = lane & 31;
  const int abase = (ra >> 4) * STRIPH + (ra & 15) * as + ((lane >> 5) << 3);
  const int alo = 16 * as;
  f32x16 acc = {0.f,0.f,0.f,0.f,0.f,0.f,0.f,0.f,0.f,0.f,0.f,0.f,0.f,0.f,0.f,0.f};
#pragma unroll
  for (int ks = 0; ks < KS_; ++ks) {
    half8 bhv, blv;
    if (ks == 0) { bhv = pbh; blv = pbl; }
    else {
      const h16* fp = wp + (((size_t)(foff + ct * KS_ + ks)) * 64 + lane) * 16;
      bhv = *(const half8*)fp;
      blv = *(const half8*)(fp + 8);
    }
    const h16* p = asrc + abase + ks * 16;
    half8 ah = *(const half8*)p;
    half8 al = *(const half8*)(p + alo);
    acc = MFMA32(al, bhv, acc);
    acc = MFMA32(ah, blv, acc);
    acc = MFMA32(ah, bhv, acc);
  }
  const int cc  = ct * 32 + (lane & 31);
  const int hl4 = (lane >> 5) << 2;
  float vr[16];
#pragma unroll
  for (int i = 0; i < 16; ++i) {
    const int rr = (i & 3) + ((i >> 2) << 3) + hl4;
    float v = acc[i] > 0.f ? acc[i] : 0.f;
    if (EPI == 1)
      v += red2p(cat + (rr >> 4) * STRIPH, cs, rr & 15, cc);
    vr[i] = v;
  }
  if (BAR) LBAR();                 // all reads of aliased region done before any write
  if (EPI <= 1) {
    const int dlo = 16 * ds;
#pragma unroll
    for (int i = 0; i < 16; ++i) {
      const int rr = (i & 3) + ((i >> 2) << 3) + hl4;
      splitw(dst + (rr >> 4) * STRIPH, (rr & 15) * ds + colb + cc, dlo, vr[i]);
    }
  } else {
#pragma unroll
    for (int i = 0; i < 16; ++i) {
      const int rr = (i & 3) + ((i >> 2) << 3) + hl4;
      gout[(size_t)(row0 + rr) * 32 + cc] = vr[i];
    }
  }
}

#define PFB(FOFF, CIDX, KS_)                                                        \
  do { const h16* _fp = wp + (((size_t)((FOFF) + (CIDX) * (KS_))) * 64 + lane) * 16; \
       pbh = *(const half8*)_fp; pbl = *(const half8*)(_fp + 8); } while (0)

__global__ __launch_bounds__(256, 3) void backbone(
    const float* __restrict__ feat, const h16* __restrict__ wp, float* __restrict__ out)
{
  __shared__ h16 lds[2 * STRIPH];  // 48128 B -> 3 blocks/CU (12 waves)
  const int lane = threadIdx.x & 63;
  const int wv   = threadIdx.x >> 6;     // 0..3
  const int row0 = blockIdx.x * 32;

  h16* E1 = lds + AE1;
  h16* E2 = lds + AE2;
  h16* CT = lds + ACT;
  h16* MR = lds + AMR;

  half8 pbh, pbl;

  // ---- P0 (w0 only): S0: feat (K=16, exact) -> CT[:,0:32]; then S1: CT -> E1
  if (wv == 0) {
    PFB(F_L0, 0, 1);
    const int ra = lane & 31;
    const float* sp = feat + (size_t)(row0 + ra) * 16 + ((lane >> 5) << 3);
    f32x4 ua = *(const f32x4*)sp, ub = *(const f32x4*)(sp + 4);
    h16 th[8], tl[8];
#pragma unroll
    for (int j = 0; j < 4; ++j) {
      h16 h;
      h = (h16)ua[j]; th[j]   = h; tl[j]   = (h16)(ua[j] - (float)h);
      h = (h16)ub[j]; th[4+j] = h; tl[4+j] = (h16)(ub[j] - (float)h);
    }
    half8 ah = *(const half8*)th, al = *(const half8*)tl;
    f32x16 a = {0.f,0.f,0.f,0.f,0.f,0.f,0.f,0.f,0.f,0.f,0.f,0.f,0.f,0.f,0.f,0.f};
    a = MFMA32(al, pbh, a); a = MFMA32(ah, pbl, a); a = MFMA32(ah, pbh, a);
    const int cl = lane & 31, hl4 = (lane >> 5) << 2;
    const int dlo = 16 * SCT;
#pragma unroll
    for (int i = 0; i < 16; ++i) {
      const int rr = (i & 3) + ((i >> 2) << 3) + hl4;
      splitw(CT + (rr >> 4) * STRIPH, (rr & 15) * SCT + cl, dlo, a[i] > 0.f ? a[i] : 0.f);
    }
    PFB(F_L1, 0, 2);
    LWAIT();                       // own writes drained before same-wave read
    layer32<2,0,0>(CT, SCT, wp, F_L1, 0, lane, pbh, pbl, E1, SE1, 0, nullptr, 0, nullptr, 0);
    PFB(F_L2, 0, 2);
  } else if (wv == 1) {
    PFB(F_L2, 1, 2);
  }
  LBAR();  // B1

  // ---- P1 (w0,w1): S2: e1(E1) -> E2   (2 x 32-col tiles)
  if (wv < 2) {
    layer32<2,0,0>(E1, SE1, wp, F_L2, wv, lane, pbh, pbl, E2, SE2, 0, nullptr, 0, nullptr, 0);
  }
  PFB(F_L3, wv, 4);
  LBAR();  // B2

  // ---- P2 (all 4): S3: e2(E2) -> CT[:,0:128]
  layer32<4,0,0>(E2, SE2, wp, F_L3, wv, lane, pbh, pbl, CT, SCT, 0, nullptr, 0, nullptr, 0);
  PFB(F_L4, wv, 8);
  LBAR();  // B3

  // ---- P3 (all 4): S4: e3(CT[0:128]) -> CT[:,128:256]  (write region disjoint)
  layer32<8,0,0>(CT, SCT, wp, F_L4, wv, lane, pbh, pbl, CT, SCT, 128, nullptr, 0, nullptr, 0);
  PFB(F_L5, wv, 16);
  LBAR();  // B4

  // ---- P4 (all 4): S5: merge3(CT[0:256]) + red -> MR[:,0:128]  (MR aliases
  //      CT[128:256): mid-stage barrier inside layer32 orders reads before writes)
  layer32<16,1,1>(CT, SCT, wp, F_L5, wv, lane, pbh, pbl, MR, SMR, 0, CT, SCT, nullptr, 0);
  if (wv < 2) PFB(F_L6, wv, 8); else PFB(F_L7, wv - 2, 4);
  LBAR();  // B5

  // ---- P5: w0,w1: L6: x2(MR[0:128]) -> CT[:,0:64]
  //          w2,w3: L7: lat2(E2)      -> CT[:,64:128]     (all regions disjoint)
  if (wv < 2) {
    layer32<8,0,0>(MR, SMR, wp, F_L6, wv, lane, pbh, pbl, CT, SCT, 0, nullptr, 0, nullptr, 0);
    PFB(F_L8, wv, 8);
  } else {
    layer32<4,0,0>(E2, SE2, wp, F_L7, wv - 2, lane, pbh, pbl, CT, SCT, 64, nullptr, 0, nullptr, 0);
  }
  LBAR();  // B6

  // ---- P6 (w0,w1): L8: merge2(CT[0:128]) + red -> MR[:,0:64]
  //      (writes phys CT[128:192): disjoint from this stage's reads)
  if (wv < 2) {
    layer32<8,1,0>(CT, SCT, wp, F_L8, wv, lane, pbh, pbl, MR, SMR, 0, CT, SCT, nullptr, 0);
  }
  if (wv == 0) PFB(F_L9, 0, 4);
  else if (wv == 1) PFB(F_L10, 0, 2);
  LBAR();  // B7

  // ---- P7: w0: L9: x1(MR[0:64]) -> CT[:,0:32];  w1: L10: lat1(E1) -> CT[:,32:64]
  if (wv == 0) {
    layer32<4,0,0>(MR, SMR, wp, F_L9, 0, lane, pbh, pbl, CT, SCT, 0, nullptr, 0, nullptr, 0);
    PFB(F_L11, 0, 4);
  } else if (wv == 1) {
    layer32<2,0,0>(E1, SE1, wp, F_L10, 0, lane, pbh, pbl, CT, SCT, 32, nullptr, 0, nullptr, 0);
  }
  LBAR();  // B8

  // ---- P8 (w0 only): L11: merge1(CT[0:64]) + red -> MR[:,0:32]  (disjoint);
  //      then L12: out(MR[0:32]) -> global fp32 [N,32]  (same-wave RAW: lgkm wait)
  if (wv == 0) {
    layer32<4,1,0>(CT, SCT, wp, F_L11, 0, lane, pbh, pbl, MR, SMR, 0, CT, SCT, nullptr, 0);
    PFB(F_L12, 0, 2);
    LWAIT();
    layer32<2,2,0>(MR, SMR, wp, F_L12, 0, lane, pbh, pbl, nullptr, 0, 0, nullptr, 0, out, row0);
  }
}

extern "C" void kernel_launch(void* const* d_in, const int* in_sizes, int n_in,
                              void* d_out, int out_size, void* d_ws, size_t ws_size,
                              hipStream_t stream) {
  (void)in_sizes; (void)n_in; (void)out_size; (void)ws_size;
  u16* packed = (u16*)d_ws;   // 350208 B

  // order: in, enc1, enc2, enc3, lat3, merge3, up3, lat2, merge2, up2, lat1, merge1, up1
  hipLaunchKernelGGL(pack_w, dim3(43), dim3(256), 0, stream,
      (const float*)d_in[2],  (const float*)d_in[3],  (const float*)d_in[4],
      (const float*)d_in[5],  (const float*)d_in[8],  (const float*)d_in[11],
      (const float*)d_in[14], (const float*)d_in[7],  (const float*)d_in[10],
      (const float*)d_in[13], (const float*)d_in[6],  (const float*)d_in[9],
      (const float*)d_in[12], packed);

  hipLaunchKernelGGL(backbone, dim3(NPAIRS), dim3(256), 0, stream,
                     (const float*)d_in[0], (const h16*)packed, (float*)d_out);
}

// Round 7
// 441.084 us; speedup vs baseline: 1.0339x; 1.0339x over previous
//
#include <hip/hip_runtime.h>

typedef unsigned short u16;
typedef unsigned int u32;
typedef _Float16 h16;
typedef __attribute__((ext_vector_type(2))) _Float16 half2v;
typedef __attribute__((ext_vector_type(8))) _Float16 half8;
typedef __attribute__((ext_vector_type(8))) unsigned short ushort8;
typedef __attribute__((ext_vector_type(4))) float f32x4;
typedef __attribute__((ext_vector_type(16))) float f32x16;

#define NPAIRS 15625            // 500000 / 32: each block = 4 waves = 2 strips (M=32)
#define STRIPH 12032            // h16 per strip arena (24064 B); block total 48128 B

// Planar hi/lo layout: value (row r in [0,16), col c) of buffer with stride S:
//   hi at base + r*S + c, lo at base + (16+r)*S + c. Strip 1 at +STRIPH.
#define AE1 0                   // 32 cols
#define SE1 40
#define AE2 1280                // 64 cols
#define SE2 72
#define ACT 3584                // 256 cols
#define SCT 264
#define AMR 3712                // MR (<=128 cols) ALIASED into CT cols [128:256)
#define SMR 264                 //   written only after all reads of that region

// 32x32x16 f16 MFMA: A row = lane&31, k = (lane>>5)*8+j; B col = lane&31, same k;
// C/D: col = lane&31, row = (reg&3) + 8*(reg>>2) + 4*(lane>>5)  [HW-verified map]
#define MFMA32(A,B,C) __builtin_amdgcn_mfma_f32_32x32x16_f16(A,B,C,0,0,0)

// light barrier: drain LDS ops only; global (B-prefetch) loads stay in flight
#define LBAR() asm volatile("s_waitcnt lgkmcnt(0)\n\ts_barrier" ::: "memory")
#define LWAIT() asm volatile("s_waitcnt lgkmcnt(0)" ::: "memory")

// ---------------- packed weight frag-pairs (f16 hi/lo, 32-wide tiles) ----------------
// fragpair f = FO[layer] + ct32*KS + ks, lane l, 32 B:
//   wp[(f*64+l)*16 + j]   = hi = f16(W[k][col])   (j=0..7)
//   wp[(f*64+l)*16 + 8+j] = lo = f16(W - (float)hi)
// col = ct32*32 + (l&31), k = ks*16 + (l>>5)*8 + j; zero-pad k >= K_actual.
#define F_L0   0
#define F_L1   1
#define F_L2   3
#define F_L3   7
#define F_L4   23
#define F_L5   55
#define F_L6   119
#define F_L7   135
#define F_L8   143
#define F_L9   159
#define F_L10  163
#define F_L11  165
#define F_L12  169
#define NFRAG  171              // d_ws bytes: 171*1024*2 = 350208

__device__ __forceinline__ u16 hb(h16 h) { union { h16 h; u16 u; } v; v.h = h; return v.u; }

__global__ __launch_bounds__(256) void pack_w(
    const float* w0, const float* w1, const float* w2, const float* w3, const float* w4,
    const float* w5, const float* w6, const float* w7, const float* w8, const float* w9,
    const float* w10, const float* w11, const float* w12, u16* __restrict__ packed)
{
  const float* ws[13] = {w0,w1,w2,w3,w4,w5,w6,w7,w8,w9,w10,w11,w12};
  const int Ka[13]  = {16,32,32,64,128,256,128,64,128,64,32,64,32};
  const int KS[13]  = {1,2,2,4,8,16,8,4,8,4,2,4,2};
  const int CO[13]  = {32,32,64,128,128,128,64,64,64,32,32,32,32};
  const int FO[13]  = {F_L0,F_L1,F_L2,F_L3,F_L4,F_L5,F_L6,F_L7,F_L8,F_L9,F_L10,F_L11,F_L12};
  int g = blockIdx.x * 256 + threadIdx.x;
  int f = g >> 6, lane = g & 63;
  if (f >= NFRAG) return;
  int layer = 0;
#pragma unroll
  for (int i = 1; i < 13; ++i) if (f >= FO[i]) layer = i;
  int fl = f - FO[layer];
  int ks = fl % KS[layer];
  int ct = fl / KS[layer];
  int cout = CO[layer];
  int col  = ct * 32 + (lane & 31);
  u16 thi[8], tlo[8];
#pragma unroll
  for (int j = 0; j < 8; ++j) {
    int k = ks * 16 + (lane >> 5) * 8 + j;
    float w = (k < Ka[layer]) ? ws[layer][k * cout + col] : 0.f;
    h16 h = (h16)w;
    h16 l = (h16)(w - (float)h);
    thi[j] = hb(h); tlo[j] = hb(l);
  }
  u16* dst = packed + ((size_t)f * 64 + lane) * 16;
  *(ushort8*)dst       = *(const ushort8*)thi;
  *(ushort8*)(dst + 8) = *(const ushort8*)tlo;
}

// ---------------- fused backbone ----------------

struct fragp { half8 h, l; };

#define LOADFP(DST, BIDX)                                                       \
  do { const h16* _fp = wp + (((size_t)(BIDX)) * 64 + lane) * 16;               \
       (DST).h = *(const half8*)_fp; (DST).l = *(const half8*)(_fp + 8); } while (0)

// prefetch first min(KS,4) fragpairs of tile (FOFF,CIDX) into pf0..pf3 (pre-barrier)
#define PFC(FOFF, CIDX, KS_)                                                    \
  do { const int _fb = (FOFF) + (CIDX) * (KS_);                                 \
       LOADFP(pf0, _fb);                                                        \
       if ((KS_) > 1) LOADFP(pf1, _fb + 1);                                     \
       if ((KS_) > 2) LOADFP(pf2, _fb + 2);                                     \
       if ((KS_) > 3) LOADFP(pf3, _fb + 3); } while (0)

// one K-step: 3 MFMAs split across two accumulator chains
#define KSTEP(BP, KSI)                                                          \
  do { const h16* _p = asrc + abase + (KSI) * 16;                               \
       half8 _ah = *(const half8*)_p;                                           \
       half8 _al = *(const half8*)(_p + alo);                                   \
       accB = MFMA32(_al, (BP).h, accB);                                        \
       accA = MFMA32(_ah, (BP).h, accA);                                        \
       accB = MFMA32(_ah, (BP).l, accB); } while (0)

__device__ __forceinline__ void splitw(h16* dst, int idx, int dlo, float v) {
  h16 h = (h16)v;
  dst[idx]       = h;
  dst[idx + dlo] = (h16)(v - (float)h);
}

__device__ __forceinline__ float red2p(const h16* catS, int cs, int r16, int cc) {
  half2v hp = *reinterpret_cast<const half2v*>(catS + r16 * cs + 2 * cc);
  half2v lp = *reinterpret_cast<const half2v*>(catS + (r16 + 16) * cs + 2 * cc);
  return (float)hp.x + (float)hp.y + (float)lp.x + (float)lp.y;
}

// One 32x32 output tile (rows = strip pair, cols = ct*32..+31), K = KS_*16.
// B fragpairs software-pipelined in 4-wide register chunks: chunk 0 arrives
// prefetched across the barrier (pf0..pf3); chunk c+1 loads issue before the
// MFMAs of chunk c. Two accumulator chains cut dependent-MFMA stalls.
// EPI 0: relu->LDS | 1: +pair-red(cat) | 2: ->global fp32
// BAR=1: block barrier between all LDS reads and epilogue writes (S5 aliasing).
template<int KS_, int EPI, int BAR>
__device__ __forceinline__ void layer32(
    const h16* __restrict__ asrc, int as,
    const h16* __restrict__ wp, int foff, int ct, int lane,
    fragp pf0, fragp pf1, fragp pf2, fragp pf3,
    h16* dst, int ds, int colb, const h16* cat, int cs,
    float* __restrict__ gout, int row0)
{
  const int ra = lane & 31;
  const int abase = (ra >> 4) * STRIPH + (ra & 15) * as + ((lane >> 5) << 3);
  const int alo = 16 * as;
  const int fb = foff + ct * KS_;
  f32x16 accA = {0.f,0.f,0.f,0.f,0.f,0.f,0.f,0.f,0.f,0.f,0.f,0.f,0.f,0.f,0.f,0.f};
  f32x16 accB = {0.f,0.f,0.f,0.f,0.f,0.f,0.f,0.f,0.f,0.f,0.f,0.f,0.f,0.f,0.f,0.f};
  fragp cur0 = pf0, cur1 = pf1, cur2 = pf2, cur3 = pf3;
  constexpr int NCH = (KS_ + 3) / 4;
#pragma unroll
  for (int ch = 0; ch < NCH; ++ch) {
    fragp nx0, nx1, nx2, nx3;
    if (ch + 1 < NCH) {           // issue next chunk's B loads before this chunk's MFMAs
      const int nb = fb + (ch + 1) * 4;
      LOADFP(nx0, nb + 0); LOADFP(nx1, nb + 1);
      LOADFP(nx2, nb + 2); LOADFP(nx3, nb + 3);
    }
    const int k0 = ch * 4;
    if (k0 + 0 < KS_) KSTEP(cur0, k0 + 0);
    if (k0 + 1 < KS_) KSTEP(cur1, k0 + 1);
    if (k0 + 2 < KS_) KSTEP(cur2, k0 + 2);
    if (k0 + 3 < KS_) KSTEP(cur3, k0 + 3);
    if (ch + 1 < NCH) { cur0 = nx0; cur1 = nx1; cur2 = nx2; cur3 = nx3; }
  }
  const int cc  = ct * 32 + (lane & 31);
  const int hl4 = (lane >> 5) << 2;
  float vr[16];
#pragma unroll
  for (int i = 0; i < 16; ++i) {
    const int rr = (i & 3) + ((i >> 2) << 3) + hl4;
    float v = accA[i] + accB[i];
    v = v > 0.f ? v : 0.f;
    if (EPI == 1)
      v += red2p(cat + (rr >> 4) * STRIPH, cs, rr & 15, cc);
    vr[i] = v;
  }
  if (BAR) LBAR();                 // all reads of aliased region done before any write
  if (EPI <= 1) {
    const int dlo = 16 * ds;
#pragma unroll
    for (int i = 0; i < 16; ++i) {
      const int rr = (i & 3) + ((i >> 2) << 3) + hl4;
      splitw(dst + (rr >> 4) * STRIPH, (rr & 15) * ds + colb + cc, dlo, vr[i]);
    }
  } else {
#pragma unroll
    for (int i = 0; i < 16; ++i) {
      const int rr = (i & 3) + ((i >> 2) << 3) + hl4;
      gout[(size_t)(row0 + rr) * 32 + cc] = vr[i];
    }
  }
}

__global__ __launch_bounds__(256, 3) void backbone(
    const float* __restrict__ feat, const h16* __restrict__ wp, float* __restrict__ out)
{
  __shared__ h16 lds[2 * STRIPH];  // 48128 B -> 3 blocks/CU (12 waves)
  const int lane = threadIdx.x & 63;
  const int wv   = threadIdx.x >> 6;     // 0..3
  const int row0 = blockIdx.x * 32;

  h16* E1 = lds + AE1;
  h16* E2 = lds + AE2;
  h16* CT = lds + ACT;
  h16* MR = lds + AMR;

  fragp pf0{}, pf1{}, pf2{}, pf3{};

  // ---- P0 (w0 only): S0: feat (K=16, exact) -> CT[:,0:32]; then S1: CT -> E1
  if (wv == 0) {
    PFC(F_L0, 0, 1);
    const int ra = lane & 31;
    const float* sp = feat + (size_t)(row0 + ra) * 16 + ((lane >> 5) << 3);
    f32x4 ua = *(const f32x4*)sp, ub = *(const f32x4*)(sp + 4);
    h16 th[8], tl[8];
#pragma unroll
    for (int j = 0; j < 4; ++j) {
      h16 h;
      h = (h16)ua[j]; th[j]   = h; tl[j]   = (h16)(ua[j] - (float)h);
      h = (h16)ub[j]; th[4+j] = h; tl[4+j] = (h16)(ub[j] - (float)h);
    }
    half8 ah = *(const half8*)th, al = *(const half8*)tl;
    f32x16 a = {0.f,0.f,0.f,0.f,0.f,0.f,0.f,0.f,0.f,0.f,0.f,0.f,0.f,0.f,0.f,0.f};
    a = MFMA32(al, pf0.h, a); a = MFMA32(ah, pf0.l, a); a = MFMA32(ah, pf0.h, a);
    const int cl = lane & 31, hl4 = (lane >> 5) << 2;
    const int dlo = 16 * SCT;
#pragma unroll
    for (int i = 0; i < 16; ++i) {
      const int rr = (i & 3) + ((i >> 2) << 3) + hl4;
      splitw(CT + (rr >> 4) * STRIPH, (rr & 15) * SCT + cl, dlo, a[i] > 0.f ? a[i] : 0.f);
    }
    PFC(F_L1, 0, 2);
    LWAIT();                       // own writes drained before same-wave read
    layer32<2,0,0>(CT, SCT, wp, F_L1, 0, lane, pf0,pf1,pf2,pf3,
                   E1, SE1, 0, nullptr, 0, nullptr, 0);
    PFC(F_L2, 0, 2);
  } else if (wv == 1) {
    PFC(F_L2, 1, 2);
  }
  LBAR();  // B1

  // ---- P1 (w0,w1): S2: e1(E1) -> E2   (2 x 32-col tiles)
  if (wv < 2) {
    layer32<2,0,0>(E1, SE1, wp, F_L2, wv, lane, pf0,pf1,pf2,pf3,
                   E2, SE2, 0, nullptr, 0, nullptr, 0);
  }
  PFC(F_L3, wv, 4);
  LBAR();  // B2

  // ---- P2 (all 4): S3: e2(E2) -> CT[:,0:128]
  layer32<4,0,0>(E2, SE2, wp, F_L3, wv, lane, pf0,pf1,pf2,pf3,
                 CT, SCT, 0, nullptr, 0, nullptr, 0);
  PFC(F_L4, wv, 8);
  LBAR();  // B3

  // ---- P3 (all 4): S4: e3(CT[0:128]) -> CT[:,128:256]  (write region disjoint)
  layer32<8,0,0>(CT, SCT, wp, F_L4, wv, lane, pf0,pf1,pf2,pf3,
                 CT, SCT, 128, nullptr, 0, nullptr, 0);
  PFC(F_L5, wv, 16);
  LBAR();  // B4

  // ---- P4 (all 4): S5: merge3(CT[0:256]) + red -> MR[:,0:128]  (MR aliases
  //      CT[128:256): mid-stage barrier inside layer32 orders reads before writes)
  layer32<16,1,1>(CT, SCT, wp, F_L5, wv, lane, pf0,pf1,pf2,pf3,
                  MR, SMR, 0, CT, SCT, nullptr, 0);
  if (wv < 2) PFC(F_L6, wv, 8); else PFC(F_L7, wv - 2, 4);
  LBAR();  // B5

  // ---- P5: w0,w1: L6: x2(MR[0:128]) -> CT[:,0:64]
  //          w2,w3: L7: lat2(E2)      -> CT[:,64:128]     (all regions disjoint)
  if (wv < 2) {
    layer32<8,0,0>(MR, SMR, wp, F_L6, wv, lane, pf0,pf1,pf2,pf3,
                   CT, SCT, 0, nullptr, 0, nullptr, 0);
    PFC(F_L8, wv, 8);
  } else {
    layer32<4,0,0>(E2, SE2, wp, F_L7, wv - 2, lane, pf0,pf1,pf2,pf3,
                   CT, SCT, 64, nullptr, 0, nullptr, 0);
  }
  LBAR();  // B6

  // ---- P6 (w0,w1): L8: merge2(CT[0:128]) + red -> MR[:,0:64]
  //      (writes phys CT[128:192): disjoint from this stage's reads)
  if (wv < 2) {
    layer32<8,1,0>(CT, SCT, wp, F_L8, wv, lane, pf0,pf1,pf2,pf3,
                   MR, SMR, 0, CT, SCT, nullptr, 0);
  }
  if (wv == 0) PFC(F_L9, 0, 4);
  else if (wv == 1) PFC(F_L10, 0, 2);
  LBAR();  // B7

  // ---- P7: w0: L9: x1(MR[0:64]) -> CT[:,0:32];  w1: L10: lat1(E1) -> CT[:,32:64]
  if (wv == 0) {
    layer32<4,0,0>(MR, SMR, wp, F_L9, 0, lane, pf0,pf1,pf2,pf3,
                   CT, SCT, 0, nullptr, 0, nullptr, 0);
    PFC(F_L11, 0, 4);
  } else if (wv == 1) {
    layer32<2,0,0>(E1, SE1, wp, F_L10, 0, lane, pf0,pf1,pf2,pf3,
                   CT, SCT, 32, nullptr, 0, nullptr, 0);
  }
  LBAR();  // B8

  // ---- P8 (w0 only): L11: merge1(CT[0:64]) + red -> MR[:,0:32]  (disjoint);
  //      then L12: out(MR[0:32]) -> global fp32 [N,32]  (same-wave RAW: lgkm wait)
  if (wv == 0) {
    layer32<4,1,0>(CT, SCT, wp, F_L11, 0, lane, pf0,pf1,pf2,pf3,
                   MR, SMR, 0, CT, SCT, nullptr, 0);
    PFC(F_L12, 0, 2);
    LWAIT();
    layer32<2,2,0>(MR, SMR, wp, F_L12, 0, lane, pf0,pf1,pf2,pf3,
                   nullptr, 0, 0, nullptr, 0, out, row0);
  }
}

extern "C" void kernel_launch(void* const* d_in, const int* in_sizes, int n_in,
                              void* d_out, int out_size, void* d_ws, size_t ws_size,
                              hipStream_t stream) {
  (void)in_sizes; (void)n_in; (void)out_size; (void)ws_size;
  u16* packed = (u16*)d_ws;   // 350208 B

  // order: in, enc1, enc2, enc3, lat3, merge3, up3, lat2, merge2, up2, lat1, merge1, up1
  hipLaunchKernelGGL(pack_w, dim3(43), dim3(256), 0, stream,
      (const float*)d_in[2],  (const float*)d_in[3],  (const float*)d_in[4],
      (const float*)d_in[5],  (const float*)d_in[8],  (const float*)d_in[11],
      (const float*)d_in[14], (const float*)d_in[7],  (const float*)d_in[10],
      (const float*)d_in[13], (const float*)d_in[6],  (const float*)d_in[9],
      (const float*)d_in[12], packed);

  hipLaunchKernelGGL(backbone, dim3(NPAIRS), dim3(256), 0, stream,
                     (const float*)d_in[0], (const h16*)packed, (float*)d_out);
}